// Round 3
// baseline (670.083 us; speedup 1.0000x reference)
//
#include <hip/hip_runtime.h>
#include <math.h>

#define B_   32
#define C_   256
#define N_   4096
#define N8_  512
#define C8_  32
#define EPS_ 1e-5f

typedef __attribute__((ext_vector_type(8))) short short8;
typedef __attribute__((ext_vector_type(4))) float f32x4;

__device__ __forceinline__ ushort f2bf(float v) {
  unsigned u = __float_as_uint(v);
  unsigned r = (u + 0x7fffu + ((u >> 16) & 1u)) >> 16;  // RNE to bf16
  return (ushort)r;
}
__device__ __forceinline__ float bf2f(ushort h) {
  return __uint_as_float(((unsigned)h) << 16);
}

// ------------- fp32 -> (bf16 hi, bf16 lo) split conversion (W) ------------
__global__ __launch_bounds__(256) void k_cvt(const float* __restrict__ src,
                                             ushort* __restrict__ hi,
                                             ushort* __restrict__ lo, int n4) {
  int i = blockIdx.x * 256 + threadIdx.x;
  int stride = gridDim.x * 256;
  for (; i < n4; i += stride) {
    float4 v = ((const float4*)src)[i];
    ushort4 h, l;
    h.x = f2bf(v.x); l.x = f2bf(v.x - bf2f(h.x));
    h.y = f2bf(v.y); l.y = f2bf(v.y - bf2f(h.y));
    h.z = f2bf(v.z); l.z = f2bf(v.z - bf2f(h.z));
    h.w = f2bf(v.w); l.w = f2bf(v.w - bf2f(h.w));
    ((ushort4*)hi)[i] = h;
    ((ushort4*)lo)[i] = l;
  }
}

// --- x converter: xh/xl flat [b][c][n], xTh transposed [b][n][c] (hi only),
// --- plus per-(b,c) max-pool partials over each 64-n block. One x read.
__global__ __launch_bounds__(256) void k_cvt_x(const float* __restrict__ x,
    ushort* __restrict__ xh, ushort* __restrict__ xl,
    ushort* __restrict__ xTh, float* __restrict__ partial) {
  int b = blockIdx.z, cb = blockIdx.y, nb = blockIdx.x;  // cb:0..3, nb:0..63
  int t = threadIdx.x;
  int cl  = t >> 2;          // 0..63
  int nl0 = (t & 3) * 16;    // 0,16,32,48
  const float* xp = x + ((size_t)b * C_ + cb * 64 + cl) * N_ + nb * 64 + nl0;
  float v[16];
  *(float4*)&v[0]  = *(const float4*)(xp + 0);
  *(float4*)&v[4]  = *(const float4*)(xp + 4);
  *(float4*)&v[8]  = *(const float4*)(xp + 8);
  *(float4*)&v[12] = *(const float4*)(xp + 12);
  ushort h[16], l[16];
  float mx = -3.402823466e+38f;
  #pragma unroll
  for (int j = 0; j < 16; ++j) {
    h[j] = f2bf(v[j]);
    l[j] = f2bf(v[j] - bf2f(h[j]));
    mx = fmaxf(mx, v[j]);
  }
  size_t fbase = ((size_t)b * C_ + cb * 64 + cl) * N_ + nb * 64 + nl0;
  *(short8*)(xh + fbase)     = *(short8*)&h[0];
  *(short8*)(xh + fbase + 8) = *(short8*)&h[8];
  *(short8*)(xl + fbase)     = *(short8*)&l[0];
  *(short8*)(xl + fbase + 8) = *(short8*)&l[8];
  // pool partial: reduce 4 threads sharing c
  mx = fmaxf(mx, __shfl_xor(mx, 1, 64));
  mx = fmaxf(mx, __shfl_xor(mx, 2, 64));
  if ((t & 3) == 0)
    partial[((size_t)b * C_ + cb * 64 + cl) * 64 + nb] = mx;
  // LDS transpose of hi
  __shared__ ushort lds[64 * 66];
  #pragma unroll
  for (int j = 0; j < 16; ++j) lds[cl * 66 + nl0 + j] = h[j];
  __syncthreads();
  int nr = t >> 2;           // 0..63
  int c0 = (t & 3) * 16;
  ushort o[16];
  #pragma unroll
  for (int j = 0; j < 16; ++j) o[j] = lds[(c0 + j) * 66 + nr];
  size_t tbase = ((size_t)b * N_ + nb * 64 + nr) * C_ + cb * 64 + c0;
  *(short8*)(xTh + tbase)     = *(short8*)&o[0];
  *(short8*)(xTh + tbase + 8) = *(short8*)&o[8];
}

// -------- kernel 1b: s = sigmoid(relu(pool@W1^T)@W2^T), pool from partials -
__global__ __launch_bounds__(256) void k_semlp(const float* __restrict__ partial,
                                               const float* __restrict__ W1,
                                               const float* __restrict__ W2,
                                               float* __restrict__ s) {
  int b = blockIdx.x, t = threadIdx.x;
  __shared__ float p[C_];
  __shared__ float h[C8_];
  float m = -3.402823466e+38f;
  const float* pp = partial + ((size_t)b * C_ + t) * 64;
  #pragma unroll
  for (int j = 0; j < 64; ++j) m = fmaxf(m, pp[j]);
  p[t] = m;
  __syncthreads();
  if (t < C8_) {
    float a = 0.f;
    for (int c = 0; c < C_; ++c) a = fmaf(p[c], W1[t * C_ + c], a);
    h[t] = fmaxf(a, 0.f);
  }
  __syncthreads();
  float a = 0.f;
  #pragma unroll
  for (int j = 0; j < C8_; ++j) a = fmaf(h[j], W2[t * C8_ + j], a);
  s[b * C_ + t] = 1.f / (1.f + __expf(-a));
}

// ------- kernel 2 (MFMA, 8-phase): q/k GEMM, no split-K, fused BN+ReLU ----
// D[b] (1024 x 256) = [Wq;Wk](1024 x K') @ X[b]^T(K' x 256), K' = 3*4096:
// tiles g 0..63 (Wh,Xh), 64..127 (Wl,Xh), 128..191 (Wh,Xl).
// Tile 256M x 128N, BK=64, 8 waves (2M x 4N), LDS 96 KiB 2-buf.
// Grid 256 flat, XCD-swizzled: all 8 role-blocks of a batch on one XCD.
// 3-bit XOR swizzle (byte ^= (row&7)<<4) both-sides; counted vmcnt.
#define GLD16(SRC, DSTP) __builtin_amdgcn_global_load_lds( \
    (const __attribute__((address_space(1))) void*)(SRC), \
    (__attribute__((address_space(3))) void*)(DSTP), 16, 0, 0)

__global__ __launch_bounds__(512, 2) void k_qk8(
    const ushort* __restrict__ wh, const ushort* __restrict__ wl,
    const ushort* __restrict__ xh, const ushort* __restrict__ xl,
    const float* __restrict__ g1, const float* __restrict__ b1,
    const float* __restrict__ m1, const float* __restrict__ v1,
    const float* __restrict__ g2, const float* __restrict__ b2,
    const float* __restrict__ m2, const float* __restrict__ v2,
    float* __restrict__ q, float* __restrict__ k) {
  __shared__ ushort lds[2][24576];   // per buf: A 256x64 @0, B 128x64 @16384
  const int bid = blockIdx.x;
  const int xcd = bid & 7, slot = bid >> 3;
  const int b  = xcd * 4 + (slot & 3);    // same-b blocks share an XCD
  const int rr_ = slot >> 2;              // role 0..7
  const int mt = rr_ >> 1, nt = rr_ & 1;  // 4 M-tiles x 2 N-tiles
  const int t = threadIdx.x;
  const int lane = t & 63, wave = t >> 6;
  const int wm = wave >> 2, wn = wave & 3;     // 2M x 4N wave grid
  const int fr = lane & 15, quad = lane >> 4;
  const int tr = t >> 3, tc = (t & 7) << 3;    // staging row / ushort col
  int aro[4], bro[2];
#pragma unroll
  for (int j = 0; j < 4; ++j) {
    int rl = j * 64 + tr;
    int cu = tc ^ ((rl & 7) << 3);
    aro[j] = (mt * 256 + rl) * N_ + cu;
  }
#pragma unroll
  for (int j = 0; j < 2; ++j) {
    int rl = j * 64 + tr;
    int cu = tc ^ ((rl & 7) << 3);
    bro[j] = (b * C_ + nt * 128 + rl) * N_ + cu;
  }
  const int dl = t * 8;                         // linear LDS dest (ushorts)

  f32x4 acc[8][2];
#pragma unroll
  for (int m = 0; m < 8; ++m)
#pragma unroll
    for (int n = 0; n < 2; ++n) acc[m][n] = (f32x4){0.f, 0.f, 0.f, 0.f};

  short8 af[4][2];
  short8 bf[2][2];

#define STG_A2(AP, K0, P, J0) do { \
    GLD16((AP) + (aro[J0] + (K0)), &lds[P][(J0) * 4096 + dl]); \
    GLD16((AP) + (aro[(J0) + 1] + (K0)), &lds[P][((J0) + 1) * 4096 + dl]); \
  } while (0)
#define STG_B2(BP, K0, P) do { \
    GLD16((BP) + (bro[0] + (K0)), &lds[P][16384 + dl]); \
    GLD16((BP) + (bro[1] + (K0)), &lds[P][16384 + 4096 + dl]); \
  } while (0)
#define VMC(N) asm volatile("s_waitcnt vmcnt(" #N ")" ::: "memory")
#define BARF() do { __builtin_amdgcn_s_barrier(); \
                    __builtin_amdgcn_sched_barrier(0); } while (0)
#define RDA(P, MH) do { \
    _Pragma("unroll") \
    for (int m = 0; m < 4; ++m) { \
      int r = wm * 128 + ((MH) * 4 + m) * 16 + fr; \
      int o = (r << 6); \
      int sw = (r & 7) << 3; \
      af[m][0] = *(const short8*)&lds[P][o + ((quad << 3) ^ sw)]; \
      af[m][1] = *(const short8*)&lds[P][o + (((quad << 3) + 32) ^ sw)]; \
    } } while (0)
#define RDB(P) do { \
    _Pragma("unroll") \
    for (int n = 0; n < 2; ++n) { \
      int c = wn * 32 + n * 16 + fr; \
      int o = 16384 + (c << 6); \
      int sw = (c & 7) << 3; \
      bf[n][0] = *(const short8*)&lds[P][o + ((quad << 3) ^ sw)]; \
      bf[n][1] = *(const short8*)&lds[P][o + (((quad << 3) + 32) ^ sw)]; \
    } } while (0)
#define MMQ(MH, NH) do { \
    __builtin_amdgcn_s_setprio(1); \
    _Pragma("unroll") \
    for (int m = 0; m < 4; ++m) { \
      acc[(MH)*4+m][NH] = __builtin_amdgcn_mfma_f32_16x16x32_bf16( \
          af[m][0], bf[NH][0], acc[(MH)*4+m][NH], 0, 0, 0); \
      acc[(MH)*4+m][NH] = __builtin_amdgcn_mfma_f32_16x16x32_bf16( \
          af[m][1], bf[NH][1], acc[(MH)*4+m][NH], 0, 0, 0); \
    } \
    __builtin_amdgcn_s_setprio(0); } while (0)

  // prologue: full tile 0 -> buf0 (6 glds); A rows 0..127 of tile 1 -> buf1
  STG_A2(wh, 0, 0, 0); STG_A2(wh, 0, 0, 2); STG_B2(xh, 0, 0);
  STG_A2(wh, 64, 1, 0);

#pragma unroll 1
  for (int i = 0; i < 96; ++i) {
    int gO = 2 * i + 1, sO = gO >> 6, kO = (gO & 63) << 6;  // buf1 tile
    const ushort* AO = (sO == 1) ? wl : wh;
    const ushort* BO = (sO == 2) ? xl : xh;
    int gE = 2 * i + 2, sE = gE >> 6, kE = (gE & 63) << 6;  // next buf0
    const ushort* AE = (sE == 1) ? wl : wh;
    const ushort* BE = (sE == 2) ? xl : xh;
    int gP = 2 * i + 3, sP = gP >> 6, kP = (gP & 63) << 6;  // next buf1
    const ushort* APn = (sP == 1) ? wl : wh;
    const bool nl = (i < 95);
    // ph0: finish buf1 A (rows 128..255); prove buf0; quadrant (0,0)
    STG_A2(AO, kO, 1, 2);
    VMC(4); BARF();
    RDA(0, 0); RDB(0); MMQ(0, 0);
    // ph1
    STG_B2(BO, kO, 1);
    MMQ(0, 1);
    // ph2
    RDA(0, 1); MMQ(1, 0);
    // ph3: buf0 read-window closed -> open write window
    BARF();
    if (nl) STG_A2(AE, kE, 0, 0);
    MMQ(1, 1);
    // ph4: prove buf1; quadrant (0,0) of buf1
    if (nl) { STG_A2(AE, kE, 0, 2); VMC(4); } else { VMC(0); }
    BARF();
    RDA(1, 0); RDB(1); MMQ(0, 0);
    // ph5
    if (nl) STG_B2(BE, kE, 0);
    MMQ(0, 1);
    // ph6
    RDA(1, 1); MMQ(1, 0);
    // ph7: buf1 read-window closed -> open write window
    BARF();
    if (nl) STG_A2(APn, kP, 1, 0);
    MMQ(1, 1);
  }

  // epilogue: BN + ReLU, write q/k directly
#pragma unroll
  for (int m = 0; m < 8; ++m) {
    int row0 = mt * 256 + wm * 128 + m * 16 + quad * 4;
#pragma unroll
    for (int r = 0; r < 4; ++r) {
      int row = row0 + r;
      bool isq = row < N8_;
      int mi = isq ? row : row - N8_;
      float sc = (isq ? g1 : g2)[mi] * rsqrtf((isq ? v1 : v2)[mi] + EPS_);
      float bi = (isq ? b1 : b2)[mi] - (isq ? m1 : m2)[mi] * sc;
      float* dp = (isq ? q : k) + ((size_t)b * N8_ + mi) * C_;
#pragma unroll
      for (int n = 0; n < 2; ++n) {
        int col = nt * 128 + wn * 32 + n * 16 + fr;
        dp[col] = fmaxf(fmaf(acc[m][n][r], sc, bi), 0.f);
      }
    }
  }
#undef STG_A2
#undef STG_B2
#undef VMC
#undef BARF
#undef RDA
#undef RDB
#undef MMQ
}

// -- kernel 3: sim -> stable softmax(-sim) -> fold alpha*s -> aff2 (bf16) --
__global__ __launch_bounds__(256) void k_simsoft(const float* __restrict__ q,
    const float* __restrict__ k, const float* __restrict__ s,
    const float* __restrict__ alpha, ushort* __restrict__ aff2) {
  int b = blockIdx.y, ct = blockIdx.x;
  int t = threadIdx.x;
  __shared__ float kT[N8_][16];
  const float* kb = k + (size_t)b * N8_ * C_;
  int c0 = ct * 16;
  for (int chunk = 0; chunk < N8_ / 16; ++chunk) {
    int row = chunk * 16 + (t >> 4);
    kT[row][t & 15] = kb[(size_t)row * C_ + c0 + (t & 15)];
  }
  __syncthreads();
  float acc[16];
  #pragma unroll
  for (int i = 0; i < 16; ++i) acc[i] = 0.f;
  const float* qb = q + (size_t)b * N8_ * C_;
  for (int kk = 0; kk < N8_; ++kk) {
    float qv = qb[(size_t)kk * C_ + t];
    float4 k0 = *(const float4*)&kT[kk][0];
    float4 k1 = *(const float4*)&kT[kk][4];
    float4 k2 = *(const float4*)&kT[kk][8];
    float4 k3 = *(const float4*)&kT[kk][12];
    acc[0]  = fmaf(k0.x, qv, acc[0]);  acc[1]  = fmaf(k0.y, qv, acc[1]);
    acc[2]  = fmaf(k0.z, qv, acc[2]);  acc[3]  = fmaf(k0.w, qv, acc[3]);
    acc[4]  = fmaf(k1.x, qv, acc[4]);  acc[5]  = fmaf(k1.y, qv, acc[5]);
    acc[6]  = fmaf(k1.z, qv, acc[6]);  acc[7]  = fmaf(k1.w, qv, acc[7]);
    acc[8]  = fmaf(k2.x, qv, acc[8]);  acc[9]  = fmaf(k2.y, qv, acc[9]);
    acc[10] = fmaf(k2.z, qv, acc[10]); acc[11] = fmaf(k2.w, qv, acc[11]);
    acc[12] = fmaf(k3.x, qv, acc[12]); acc[13] = fmaf(k3.y, qv, acc[13]);
    acc[14] = fmaf(k3.z, qv, acc[14]); acc[15] = fmaf(k3.w, qv, acc[15]);
  }
  int lane = t & 63, wid = t >> 6;
  __shared__ float wmin[16][4];
  __shared__ float wsum[16][4];
  #pragma unroll
  for (int i = 0; i < 16; ++i) {
    float v = acc[i];
    for (int off = 32; off > 0; off >>= 1) v = fminf(v, __shfl_xor(v, off, 64));
    if (lane == 0) wmin[i][wid] = v;
  }
  __syncthreads();
  float w[16];
  #pragma unroll
  for (int i = 0; i < 16; ++i) {
    float m = fminf(fminf(wmin[i][0], wmin[i][1]), fminf(wmin[i][2], wmin[i][3]));
    w[i] = __expf(m - acc[i]);
  }
  #pragma unroll
  for (int i = 0; i < 16; ++i) {
    float v = w[i];
    for (int off = 32; off > 0; off >>= 1) v += __shfl_xor(v, off, 64);
    if (lane == 0) wsum[i][wid] = v;
  }
  __syncthreads();
  float fac = alpha[0] * s[b * C_ + t];
  ushort* ab = aff2 + (size_t)b * C_ * C_;
  #pragma unroll
  for (int i = 0; i < 16; ++i) {
    float Z = wsum[i][0] + wsum[i][1] + wsum[i][2] + wsum[i][3];
    ab[(size_t)(c0 + i) * C_ + t] = f2bf(fac * w[i] / Z);
  }
}

// ------- kernel 4 (MFMA): out = aff2 @ x + x, A=aff_bf16, B=xTh -----------
__global__ __launch_bounds__(256) void k_out_mfma(
    const ushort* __restrict__ aff, const ushort* __restrict__ xTh,
    const float* __restrict__ x, float* __restrict__ out) {
  int b  = blockIdx.z;
  int cb = blockIdx.y;  // 0..1 : c block of 128
  int nb = blockIdx.x;  // 0..31: n block of 128
  __shared__ ushort Ah[128 * 32];
  __shared__ ushort Bh[128 * 32];
  int t = threadIdx.x, wave = t >> 6, lane = t & 63;
  int wr = (wave >> 1) * 64, wc = (wave & 1) * 64;
  int srow = wave * 16 + (lane >> 2);
  int skof = (lane & 3) * 8;
  size_t aoff = ((size_t)b * C_ + cb * 128 + srow) * C_ + skof;
  size_t boff = ((size_t)b * N_ + nb * 128 + srow) * C_ + skof;
  int lb0 = (wave * 16) * 32;

  f32x4 acc[4][4];
  #pragma unroll
  for (int mi = 0; mi < 4; ++mi)
    #pragma unroll
    for (int ni = 0; ni < 4; ++ni)
      acc[mi][ni] = (f32x4){0.f, 0.f, 0.f, 0.f};

  int fr = lane & 15, quad = lane >> 4;
  for (int k0 = 0; k0 < C_; k0 += 32) {
    #pragma unroll
    for (int seg = 0; seg < 2; ++seg) {
      size_t ga = aoff + (size_t)seg * 64 * C_ + k0;
      size_t gb = boff + (size_t)seg * 64 * C_ + k0;
      int lb = lb0 + seg * 64 * 32;
      __builtin_amdgcn_global_load_lds(
          (const __attribute__((address_space(1))) void*)(aff + ga),
          (__attribute__((address_space(3))) void*)(&Ah[lb]), 16, 0, 0);
      __builtin_amdgcn_global_load_lds(
          (const __attribute__((address_space(1))) void*)(xTh + gb),
          (__attribute__((address_space(3))) void*)(&Bh[lb]), 16, 0, 0);
    }
    __syncthreads();
    short8 af[4], bf[4];
    #pragma unroll
    for (int i = 0; i < 4; ++i) {
      af[i] = *(const short8*)&Ah[(wr + i * 16 + fr) * 32 + quad * 8];
      bf[i] = *(const short8*)&Bh[(wc + i * 16 + fr) * 32 + quad * 8];
    }
    #pragma unroll
    for (int mi = 0; mi < 4; ++mi)
      #pragma unroll
      for (int ni = 0; ni < 4; ++ni)
        acc[mi][ni] = __builtin_amdgcn_mfma_f32_16x16x32_bf16(
            af[mi], bf[ni], acc[mi][ni], 0, 0, 0);
    __syncthreads();
  }

  const float* xb = x + (size_t)b * C_ * N_;
  float* ob = out + (size_t)b * C_ * N_;
  int c0 = cb * 128 + wr + quad * 4;
  int n0 = nb * 128 + wc + fr;
  #pragma unroll
  for (int mi = 0; mi < 4; ++mi) {
    #pragma unroll
    for (int r = 0; r < 4; ++r) {
      int c = c0 + mi * 16 + r;
      #pragma unroll
      for (int ni = 0; ni < 4; ++ni) {
        int n = n0 + ni * 16;
        ob[(size_t)c * N_ + n] = acc[mi][ni][r] + xb[(size_t)c * N_ + n];
      }
    }
  }
}

extern "C" void kernel_launch(void* const* d_in, const int* in_sizes, int n_in,
                              void* d_out, int out_size, void* d_ws, size_t ws_size,
                              hipStream_t stream) {
  const float* x     = (const float*)d_in[0];
  const float* Wq    = (const float*)d_in[1];
  const float* g1    = (const float*)d_in[2];
  const float* b1    = (const float*)d_in[3];
  const float* m1    = (const float*)d_in[4];
  const float* v1    = (const float*)d_in[5];
  const float* Wk    = (const float*)d_in[6];
  const float* g2    = (const float*)d_in[7];
  const float* b2    = (const float*)d_in[8];
  const float* m2    = (const float*)d_in[9];
  const float* v2    = (const float*)d_in[10];
  const float* W1    = (const float*)d_in[11];
  const float* W2    = (const float*)d_in[12];
  const float* alpha = (const float*)d_in[13];
  float* out = (float*)d_out;

  float* ws      = (float*)d_ws;
  float* q       = ws;                                  // 4,194,304 f
  float* kbuf    = q + (size_t)B_ * N8_ * C_;           // 4,194,304 f
  float* partial = kbuf + (size_t)B_ * N8_ * C_;        //   524,288 f
  float* s       = partial + (size_t)B_ * C_ * 64;      //     8,192 f
  ushort* aff    = (ushort*)(s + B_ * C_);              // 2,097,152 u16
  ushort* xh     = aff + (size_t)B_ * C_ * C_;          // 33,554,432 u16
  ushort* xl     = xh + (size_t)B_ * C_ * N_;
  ushort* xTh    = xl + (size_t)B_ * C_ * N_;           // 33,554,432 u16
  ushort* wh     = xTh + (size_t)B_ * C_ * N_;          // 4,194,304 u16
  ushort* wl     = wh + (size_t)2 * N8_ * N_;

  k_cvt_x<<<dim3(64, 4, B_), 256, 0, stream>>>(x, xh, xl, xTh, partial);
  k_cvt<<<dim3(1024), 256, 0, stream>>>(Wq, wh, wl, N8_ * N_ / 4);
  k_cvt<<<dim3(1024), 256, 0, stream>>>(Wk, wh + (size_t)N8_ * N_,
                                        wl + (size_t)N8_ * N_, N8_ * N_ / 4);
  k_semlp<<<dim3(B_), 256, 0, stream>>>(partial, W1, W2, s);
  k_qk8<<<dim3(256), 512, 0, stream>>>(wh, wl, xh, xl,
                                       g1, b1, m1, v1,
                                       g2, b2, m2, v2, q, kbuf);
  k_simsoft<<<dim3(16, B_), 256, 0, stream>>>(q, kbuf, s, alpha, aff);
  k_out_mfma<<<dim3(32, 2, B_), 256, 0, stream>>>(aff, xTh, x, out);
}

// Round 4
// 648.884 us; speedup vs baseline: 1.0327x; 1.0327x over previous
//
#include <hip/hip_runtime.h>
#include <math.h>

#define B_   32
#define C_   256
#define N_   4096
#define N8_  512
#define C8_  32
#define EPS_ 1e-5f

typedef __attribute__((ext_vector_type(8))) short short8;
typedef __attribute__((ext_vector_type(4))) float f32x4;

__device__ __forceinline__ ushort f2bf(float v) {
  unsigned u = __float_as_uint(v);
  unsigned r = (u + 0x7fffu + ((u >> 16) & 1u)) >> 16;  // RNE to bf16
  return (ushort)r;
}
__device__ __forceinline__ float bf2f(ushort h) {
  return __uint_as_float(((unsigned)h) << 16);
}

// ------------- fp32 -> (bf16 hi, bf16 lo) split conversion (W) ------------
__global__ __launch_bounds__(256) void k_cvt(const float* __restrict__ src,
                                             ushort* __restrict__ hi,
                                             ushort* __restrict__ lo, int n4) {
  int i = blockIdx.x * 256 + threadIdx.x;
  int stride = gridDim.x * 256;
  for (; i < n4; i += stride) {
    float4 v = ((const float4*)src)[i];
    ushort4 h, l;
    h.x = f2bf(v.x); l.x = f2bf(v.x - bf2f(h.x));
    h.y = f2bf(v.y); l.y = f2bf(v.y - bf2f(h.y));
    h.z = f2bf(v.z); l.z = f2bf(v.z - bf2f(h.z));
    h.w = f2bf(v.w); l.w = f2bf(v.w - bf2f(h.w));
    ((ushort4*)hi)[i] = h;
    ((ushort4*)lo)[i] = l;
  }
}

// --- x converter: xh/xl flat [b][c][n], xTh transposed [b][n][c] (hi only),
// --- plus per-(b,c) max-pool partials over each 64-n block. One x read.
__global__ __launch_bounds__(256) void k_cvt_x(const float* __restrict__ x,
    ushort* __restrict__ xh, ushort* __restrict__ xl,
    ushort* __restrict__ xTh, float* __restrict__ partial) {
  int b = blockIdx.z, cb = blockIdx.y, nb = blockIdx.x;  // cb:0..3, nb:0..63
  int t = threadIdx.x;
  int cl  = t >> 2;          // 0..63
  int nl0 = (t & 3) * 16;    // 0,16,32,48
  const float* xp = x + ((size_t)b * C_ + cb * 64 + cl) * N_ + nb * 64 + nl0;
  float v[16];
  *(float4*)&v[0]  = *(const float4*)(xp + 0);
  *(float4*)&v[4]  = *(const float4*)(xp + 4);
  *(float4*)&v[8]  = *(const float4*)(xp + 8);
  *(float4*)&v[12] = *(const float4*)(xp + 12);
  ushort h[16], l[16];
  float mx = -3.402823466e+38f;
  #pragma unroll
  for (int j = 0; j < 16; ++j) {
    h[j] = f2bf(v[j]);
    l[j] = f2bf(v[j] - bf2f(h[j]));
    mx = fmaxf(mx, v[j]);
  }
  size_t fbase = ((size_t)b * C_ + cb * 64 + cl) * N_ + nb * 64 + nl0;
  *(short8*)(xh + fbase)     = *(short8*)&h[0];
  *(short8*)(xh + fbase + 8) = *(short8*)&h[8];
  *(short8*)(xl + fbase)     = *(short8*)&l[0];
  *(short8*)(xl + fbase + 8) = *(short8*)&l[8];
  // pool partial: reduce 4 threads sharing c
  mx = fmaxf(mx, __shfl_xor(mx, 1, 64));
  mx = fmaxf(mx, __shfl_xor(mx, 2, 64));
  if ((t & 3) == 0)
    partial[((size_t)b * C_ + cb * 64 + cl) * 64 + nb] = mx;
  // LDS transpose of hi
  __shared__ ushort lds[64 * 66];
  #pragma unroll
  for (int j = 0; j < 16; ++j) lds[cl * 66 + nl0 + j] = h[j];
  __syncthreads();
  int nr = t >> 2;           // 0..63
  int c0 = (t & 3) * 16;
  ushort o[16];
  #pragma unroll
  for (int j = 0; j < 16; ++j) o[j] = lds[(c0 + j) * 66 + nr];
  size_t tbase = ((size_t)b * N_ + nb * 64 + nr) * C_ + cb * 64 + c0;
  *(short8*)(xTh + tbase)     = *(short8*)&o[0];
  *(short8*)(xTh + tbase + 8) = *(short8*)&o[8];
}

// -------- kernel 1b: s = sigmoid(relu(pool@W1^T)@W2^T), pool from partials -
__global__ __launch_bounds__(256) void k_semlp(const float* __restrict__ partial,
                                               const float* __restrict__ W1,
                                               const float* __restrict__ W2,
                                               float* __restrict__ s) {
  int b = blockIdx.x, t = threadIdx.x;
  __shared__ float p[C_];
  __shared__ float h[C8_];
  float m = -3.402823466e+38f;
  const float* pp = partial + ((size_t)b * C_ + t) * 64;
  #pragma unroll
  for (int j = 0; j < 64; ++j) m = fmaxf(m, pp[j]);
  p[t] = m;
  __syncthreads();
  if (t < C8_) {
    float a = 0.f;
    for (int c = 0; c < C_; ++c) a = fmaf(p[c], W1[t * C_ + c], a);
    h[t] = fmaxf(a, 0.f);
  }
  __syncthreads();
  float a = 0.f;
  #pragma unroll
  for (int j = 0; j < C8_; ++j) a = fmaf(h[j], W2[t * C8_ + j], a);
  s[b * C_ + t] = 1.f / (1.f + __expf(-a));
}

// ------- kernel 2 (MFMA, 8-phase): split-K partial GEMM for q|k ----------
// D[b] (1024 x 256) = [Wq;Wk](1024 x K') @ X[b]^T(K' x 256), K' = 3*4096:
// seg0 (Wh,Xh), seg1 (Wl,Xh), seg2 (Wh,Xl).  256x256 tile, BK=64, 8 waves.
// split-K=2 -> 256 blocks (1/CU).  3-bit XOR swizzle (byte ^= (row&7)<<4),
// both-sides.  Counted vmcnt.  XCD-swizzled flat grid: the 8 role-blocks
// (4 mt x 2 ks) of each batch land on one XCD -> X[b] panels L2-local.
#define GLD16(SRC, DSTP) __builtin_amdgcn_global_load_lds( \
    (const __attribute__((address_space(1))) void*)(SRC), \
    (__attribute__((address_space(3))) void*)(DSTP), 16, 0, 0)

__global__ __launch_bounds__(512, 2) void k_qk8(
    const ushort* __restrict__ wh, const ushort* __restrict__ wl,
    const ushort* __restrict__ xh, const ushort* __restrict__ xl,
    float* __restrict__ part) {
  __shared__ ushort lds[2][2][256 * 64];   // [buf][A|B][row*64+col] 128 KiB
  const int bid = blockIdx.x;
  const int xcd = bid & 7, slot = bid >> 3;
  const int b   = xcd * 4 + (slot & 3);    // same-b blocks share an XCD
  const int role = slot >> 2;              // 0..7
  const int ks = role & 1;                 // split-K half
  const int mt = role >> 1;                // 256-row M tile
  const int t = threadIdx.x;
  const int lane = t & 63, wave = t >> 6;
  const int wm = wave >> 2, wn = wave & 3;     // 2M x 4N wave grid
  const int fr = lane & 15, quad = lane >> 4;
  const int R0 = mt * 256;
  const int tr = t >> 3, tc = (t & 7) << 3;    // staging row / ushort col
  int aro[4], bro[4];
#pragma unroll
  for (int j = 0; j < 4; ++j) {
    int rl = j * 64 + tr;                       // tile-local row 0..255
    int cu = tc ^ ((rl & 7) << 3);              // pre-swizzled source col
    aro[j] = (R0 + rl) * N_ + cu;
    bro[j] = (b * C_ + rl) * N_ + cu;
  }
  const int dl = t * 8;                         // linear LDS dest (ushorts)

  f32x4 acc[8][4];
#pragma unroll
  for (int m = 0; m < 8; ++m)
#pragma unroll
    for (int n = 0; n < 4; ++n) acc[m][n] = (f32x4){0.f, 0.f, 0.f, 0.f};

  short8 af[4][2];
  short8 bf[2][2][2];

#define STG_A(AP, K0, P, J0) do { \
    GLD16((AP) + (aro[J0] + (K0)), &lds[P][0][(J0) * 4096 + dl]); \
    GLD16((AP) + (aro[(J0) + 1] + (K0)), &lds[P][0][((J0) + 1) * 4096 + dl]); \
  } while (0)
#define STG_B(BP, K0, P, J0) do { \
    GLD16((BP) + (bro[J0] + (K0)), &lds[P][1][(J0) * 4096 + dl]); \
    GLD16((BP) + (bro[(J0) + 1] + (K0)), &lds[P][1][((J0) + 1) * 4096 + dl]); \
  } while (0)
#define VMC(N) asm volatile("s_waitcnt vmcnt(" #N ")" ::: "memory")
#define BARF() do { __builtin_amdgcn_s_barrier(); \
                    __builtin_amdgcn_sched_barrier(0); } while (0)
#define RDA(P, MH) do { \
    _Pragma("unroll") \
    for (int m = 0; m < 4; ++m) { \
      int r = wm * 128 + ((MH) * 4 + m) * 16 + fr; \
      int o = (r << 6); \
      int sw = (r & 7) << 3; \
      af[m][0] = *(const short8*)&lds[P][0][o + ((quad << 3) ^ sw)]; \
      af[m][1] = *(const short8*)&lds[P][0][o + (((quad << 3) + 32) ^ sw)]; \
    } } while (0)
#define RDB(P, NH) do { \
    _Pragma("unroll") \
    for (int n = 0; n < 2; ++n) { \
      int c = wn * 64 + ((NH) * 2 + n) * 16 + fr; \
      int o = (c << 6); \
      int sw = (c & 7) << 3; \
      bf[NH][n][0] = *(const short8*)&lds[P][1][o + ((quad << 3) ^ sw)]; \
      bf[NH][n][1] = *(const short8*)&lds[P][1][o + (((quad << 3) + 32) ^ sw)]; \
    } } while (0)
#define MMQ(MH, NH) do { \
    __builtin_amdgcn_s_setprio(1); \
    _Pragma("unroll") \
    for (int m = 0; m < 4; ++m) \
      _Pragma("unroll") \
      for (int n = 0; n < 2; ++n) { \
        acc[(MH)*4+m][(NH)*2+n] = __builtin_amdgcn_mfma_f32_16x16x32_bf16( \
            af[m][0], bf[NH][n][0], acc[(MH)*4+m][(NH)*2+n], 0, 0, 0); \
        acc[(MH)*4+m][(NH)*2+n] = __builtin_amdgcn_mfma_f32_16x16x32_bf16( \
            af[m][1], bf[NH][n][1], acc[(MH)*4+m][(NH)*2+n], 0, 0, 0); \
      } \
    __builtin_amdgcn_s_setprio(0); } while (0)

  const int gbase = ks * 96;   // 96 K-tiles of 64 per block (K'=12288 total)
  // prologue: full tile gbase -> buf0 ; unit0 (A rows 0..127) of gbase+1 -> buf1
  {
    int g = gbase, sg = g >> 6, k0 = (g & 63) << 6;
    const ushort* Ap = (sg == 1) ? wl : wh;
    const ushort* Bp = (sg == 2) ? xl : xh;
    STG_A(Ap, k0, 0, 0); STG_A(Ap, k0, 0, 2);
    STG_B(Bp, k0, 0, 0); STG_B(Bp, k0, 0, 2);
    int g1 = gbase + 1, s1 = g1 >> 6, k1 = (g1 & 63) << 6;
    const ushort* Ap1 = (s1 == 1) ? wl : wh;
    STG_A(Ap1, k1, 1, 0);
  }

#pragma unroll 1
  for (int i = 0; i < 48; ++i) {
    int gO = gbase + 2 * i + 1, sO = gO >> 6, kO = (gO & 63) << 6;  // buf1 tile
    const ushort* AO = (sO == 1) ? wl : wh;
    const ushort* BO = (sO == 2) ? xl : xh;
    int gE = gbase + 2 * i + 2, sE = gE >> 6, kE = (gE & 63) << 6;  // next buf0
    const ushort* AE = (sE == 1) ? wl : wh;
    const ushort* BE = (sE == 2) ? xl : xh;
    int gP = gbase + 2 * i + 3, sP = gP >> 6, kP = (gP & 63) << 6;  // next buf1
    const ushort* APn = (sP == 1) ? wl : wh;
    const bool nl = (i < 47);
    // ph0: finish buf1 staging (A hi-half); prove buf0 tile; quadrant (0,0)
    STG_A(AO, kO, 1, 2);
    VMC(4); BARF();
    RDA(0, 0); RDB(0, 0); MMQ(0, 0);
    // ph1
    STG_B(BO, kO, 1, 0);
    RDB(0, 1); MMQ(0, 1);
    // ph2
    STG_B(BO, kO, 1, 2);
    RDA(0, 1); MMQ(1, 0);
    // ph3: buf0 read-window closed -> open its write window
    BARF();
    if (nl) STG_A(AE, kE, 0, 0);
    MMQ(1, 1);
    // ph4: prove buf1 tile; quadrant (0,0) of buf1
    if (nl) { STG_A(AE, kE, 0, 2); VMC(4); } else { VMC(0); }
    BARF();
    RDA(1, 0); RDB(1, 0); MMQ(0, 0);
    // ph5
    if (nl) STG_B(BE, kE, 0, 0);
    RDB(1, 1); MMQ(0, 1);
    // ph6
    if (nl) STG_B(BE, kE, 0, 2);
    RDA(1, 1); MMQ(1, 0);
    // ph7: buf1 read-window closed -> open its write window
    BARF();
    if (nl) STG_A(APn, kP, 1, 0);
    MMQ(1, 1);
  }

  float* dst = part + ((size_t)(ks * 32 + b) * 1024) * 256;
#pragma unroll
  for (int m = 0; m < 8; ++m) {
    int row0 = R0 + wm * 128 + m * 16 + quad * 4;
#pragma unroll
    for (int r = 0; r < 4; ++r) {
#pragma unroll
      for (int n = 0; n < 4; ++n) {
        int col = wn * 64 + n * 16 + fr;
        dst[(size_t)(row0 + r) * 256 + col] = acc[m][n][r];
      }
    }
  }
#undef STG_A
#undef STG_B
#undef VMC
#undef BARF
#undef RDA
#undef RDB
#undef MMQ
}

// ------- kernel 2b: reduce split-K partials + BN + relu -> q, k -----------
__global__ __launch_bounds__(256) void k_qkred(
    const float* __restrict__ part,
    const float* __restrict__ g1, const float* __restrict__ b1,
    const float* __restrict__ m1, const float* __restrict__ v1,
    const float* __restrict__ g2, const float* __restrict__ b2,
    const float* __restrict__ m2, const float* __restrict__ v2,
    float* __restrict__ q, float* __restrict__ k) {
  int i = blockIdx.x * 256 + threadIdx.x;   // f32x4 index, 2,097,152 total
  int b = i >> 16;
  int rem = i & 65535;
  int row = rem >> 6;                       // 0..1023
  int c4 = (rem & 63) << 2;
  const float4* p = (const float4*)part;
  float4 u = p[i];
  float4 w = p[i + 2097152];
  bool isq = row < 512;
  int m = isq ? row : row - 512;
  float sc = (isq ? g1 : g2)[m] * rsqrtf((isq ? v1 : v2)[m] + EPS_);
  float bi = (isq ? b1 : b2)[m] - (isq ? m1 : m2)[m] * sc;
  float4 o;
  o.x = fmaxf(fmaf(u.x + w.x, sc, bi), 0.f);
  o.y = fmaxf(fmaf(u.y + w.y, sc, bi), 0.f);
  o.z = fmaxf(fmaf(u.z + w.z, sc, bi), 0.f);
  o.w = fmaxf(fmaf(u.w + w.w, sc, bi), 0.f);
  float* d = (isq ? q : k) + ((size_t)b * N8_ + m) * C_ + c4;
  *(float4*)d = o;
}

// -- kernel 3: sim -> stable softmax(-sim) -> fold alpha*s -> aff2 (bf16) --
__global__ __launch_bounds__(256) void k_simsoft(const float* __restrict__ q,
    const float* __restrict__ k, const float* __restrict__ s,
    const float* __restrict__ alpha, ushort* __restrict__ aff2) {
  int b = blockIdx.y, ct = blockIdx.x;
  int t = threadIdx.x;
  __shared__ float kT[N8_][16];
  const float* kb = k + (size_t)b * N8_ * C_;
  int c0 = ct * 16;
  for (int chunk = 0; chunk < N8_ / 16; ++chunk) {
    int row = chunk * 16 + (t >> 4);
    kT[row][t & 15] = kb[(size_t)row * C_ + c0 + (t & 15)];
  }
  __syncthreads();
  float acc[16];
  #pragma unroll
  for (int i = 0; i < 16; ++i) acc[i] = 0.f;
  const float* qb = q + (size_t)b * N8_ * C_;
  for (int kk = 0; kk < N8_; ++kk) {
    float qv = qb[(size_t)kk * C_ + t];
    float4 k0 = *(const float4*)&kT[kk][0];
    float4 k1 = *(const float4*)&kT[kk][4];
    float4 k2 = *(const float4*)&kT[kk][8];
    float4 k3 = *(const float4*)&kT[kk][12];
    acc[0]  = fmaf(k0.x, qv, acc[0]);  acc[1]  = fmaf(k0.y, qv, acc[1]);
    acc[2]  = fmaf(k0.z, qv, acc[2]);  acc[3]  = fmaf(k0.w, qv, acc[3]);
    acc[4]  = fmaf(k1.x, qv, acc[4]);  acc[5]  = fmaf(k1.y, qv, acc[5]);
    acc[6]  = fmaf(k1.z, qv, acc[6]);  acc[7]  = fmaf(k1.w, qv, acc[7]);
    acc[8]  = fmaf(k2.x, qv, acc[8]);  acc[9]  = fmaf(k2.y, qv, acc[9]);
    acc[10] = fmaf(k2.z, qv, acc[10]); acc[11] = fmaf(k2.w, qv, acc[11]);
    acc[12] = fmaf(k3.x, qv, acc[12]); acc[13] = fmaf(k3.y, qv, acc[13]);
    acc[14] = fmaf(k3.z, qv, acc[14]); acc[15] = fmaf(k3.w, qv, acc[15]);
  }
  int lane = t & 63, wid = t >> 6;
  __shared__ float wmin[16][4];
  __shared__ float wsum[16][4];
  #pragma unroll
  for (int i = 0; i < 16; ++i) {
    float v = acc[i];
    for (int off = 32; off > 0; off >>= 1) v = fminf(v, __shfl_xor(v, off, 64));
    if (lane == 0) wmin[i][wid] = v;
  }
  __syncthreads();
  float w[16];
  #pragma unroll
  for (int i = 0; i < 16; ++i) {
    float m = fminf(fminf(wmin[i][0], wmin[i][1]), fminf(wmin[i][2], wmin[i][3]));
    w[i] = __expf(m - acc[i]);
  }
  #pragma unroll
  for (int i = 0; i < 16; ++i) {
    float v = w[i];
    for (int off = 32; off > 0; off >>= 1) v += __shfl_xor(v, off, 64);
    if (lane == 0) wsum[i][wid] = v;
  }
  __syncthreads();
  float fac = alpha[0] * s[b * C_ + t];
  ushort* ab = aff2 + (size_t)b * C_ * C_;
  #pragma unroll
  for (int i = 0; i < 16; ++i) {
    float Z = wsum[i][0] + wsum[i][1] + wsum[i][2] + wsum[i][3];
    ab[(size_t)(c0 + i) * C_ + t] = f2bf(fac * w[i] / Z);
  }
}

// ------- kernel 4 (MFMA): out = aff2 @ x + x, A=aff_bf16, B=xTh -----------
__global__ __launch_bounds__(256) void k_out_mfma(
    const ushort* __restrict__ aff, const ushort* __restrict__ xTh,
    const float* __restrict__ x, float* __restrict__ out) {
  int b  = blockIdx.z;
  int cb = blockIdx.y;  // 0..1 : c block of 128
  int nb = blockIdx.x;  // 0..31: n block of 128
  __shared__ ushort Ah[128 * 32];
  __shared__ ushort Bh[128 * 32];
  int t = threadIdx.x, wave = t >> 6, lane = t & 63;
  int wr = (wave >> 1) * 64, wc = (wave & 1) * 64;
  int srow = wave * 16 + (lane >> 2);
  int skof = (lane & 3) * 8;
  size_t aoff = ((size_t)b * C_ + cb * 128 + srow) * C_ + skof;
  size_t boff = ((size_t)b * N_ + nb * 128 + srow) * C_ + skof;
  int lb0 = (wave * 16) * 32;

  f32x4 acc[4][4];
  #pragma unroll
  for (int mi = 0; mi < 4; ++mi)
    #pragma unroll
    for (int ni = 0; ni < 4; ++ni)
      acc[mi][ni] = (f32x4){0.f, 0.f, 0.f, 0.f};

  int fr = lane & 15, quad = lane >> 4;
  for (int k0 = 0; k0 < C_; k0 += 32) {
    #pragma unroll
    for (int seg = 0; seg < 2; ++seg) {
      size_t ga = aoff + (size_t)seg * 64 * C_ + k0;
      size_t gb = boff + (size_t)seg * 64 * C_ + k0;
      int lb = lb0 + seg * 64 * 32;
      __builtin_amdgcn_global_load_lds(
          (const __attribute__((address_space(1))) void*)(aff + ga),
          (__attribute__((address_space(3))) void*)(&Ah[lb]), 16, 0, 0);
      __builtin_amdgcn_global_load_lds(
          (const __attribute__((address_space(1))) void*)(xTh + gb),
          (__attribute__((address_space(3))) void*)(&Bh[lb]), 16, 0, 0);
    }
    __syncthreads();
    short8 af[4], bf[4];
    #pragma unroll
    for (int i = 0; i < 4; ++i) {
      af[i] = *(const short8*)&Ah[(wr + i * 16 + fr) * 32 + quad * 8];
      bf[i] = *(const short8*)&Bh[(wc + i * 16 + fr) * 32 + quad * 8];
    }
    #pragma unroll
    for (int mi = 0; mi < 4; ++mi)
      #pragma unroll
      for (int ni = 0; ni < 4; ++ni)
        acc[mi][ni] = __builtin_amdgcn_mfma_f32_16x16x32_bf16(
            af[mi], bf[ni], acc[mi][ni], 0, 0, 0);
    __syncthreads();
  }

  const float* xb = x + (size_t)b * C_ * N_;
  float* ob = out + (size_t)b * C_ * N_;
  int c0 = cb * 128 + wr + quad * 4;
  int n0 = nb * 128 + wc + fr;
  #pragma unroll
  for (int mi = 0; mi < 4; ++mi) {
    #pragma unroll
    for (int r = 0; r < 4; ++r) {
      int c = c0 + mi * 16 + r;
      #pragma unroll
      for (int ni = 0; ni < 4; ++ni) {
        int n = n0 + ni * 16;
        ob[(size_t)c * N_ + n] = acc[mi][ni][r] + xb[(size_t)c * N_ + n];
      }
    }
  }
}

extern "C" void kernel_launch(void* const* d_in, const int* in_sizes, int n_in,
                              void* d_out, int out_size, void* d_ws, size_t ws_size,
                              hipStream_t stream) {
  const float* x     = (const float*)d_in[0];
  const float* Wq    = (const float*)d_in[1];
  const float* g1    = (const float*)d_in[2];
  const float* b1    = (const float*)d_in[3];
  const float* m1    = (const float*)d_in[4];
  const float* v1    = (const float*)d_in[5];
  const float* Wk    = (const float*)d_in[6];
  const float* g2    = (const float*)d_in[7];
  const float* b2    = (const float*)d_in[8];
  const float* m2    = (const float*)d_in[9];
  const float* v2    = (const float*)d_in[10];
  const float* W1    = (const float*)d_in[11];
  const float* W2    = (const float*)d_in[12];
  const float* alpha = (const float*)d_in[13];
  float* out = (float*)d_out;

  float* ws      = (float*)d_ws;
  float* q       = ws;                                  // 4,194,304 f
  float* kbuf    = q + (size_t)B_ * N8_ * C_;           // 4,194,304 f
  float* partial = kbuf + (size_t)B_ * N8_ * C_;        //   524,288 f
  float* s       = partial + (size_t)B_ * C_ * 64;      //     8,192 f
  ushort* aff    = (ushort*)(s + B_ * C_);              // 2,097,152 u16
  ushort* xh     = aff + (size_t)B_ * C_ * C_;          // 33,554,432 u16
  ushort* xl     = xh + (size_t)B_ * C_ * N_;
  ushort* xTh    = xl + (size_t)B_ * C_ * N_;           // 33,554,432 u16
  ushort* wh     = xTh + (size_t)B_ * C_ * N_;          // 4,194,304 u16
  ushort* wl     = wh + (size_t)2 * N8_ * N_;

  // split-K GEMM partials live in d_out until k_out_mfma overwrites it
  float* gpart = (float*)d_out;                         // 2*32*1024*256 f

  k_cvt_x<<<dim3(64, 4, B_), 256, 0, stream>>>(x, xh, xl, xTh, partial);
  k_cvt<<<dim3(1024), 256, 0, stream>>>(Wq, wh, wl, N8_ * N_ / 4);
  k_cvt<<<dim3(1024), 256, 0, stream>>>(Wk, wh + (size_t)N8_ * N_,
                                        wl + (size_t)N8_ * N_, N8_ * N_ / 4);
  k_semlp<<<dim3(B_), 256, 0, stream>>>(partial, W1, W2, s);
  k_qk8<<<dim3(256), 512, 0, stream>>>(wh, wl, xh, xl, gpart);
  k_qkred<<<dim3(8192), 256, 0, stream>>>(gpart, g1, b1, m1, v1,
                                          g2, b2, m2, v2, q, kbuf);
  k_simsoft<<<dim3(16, B_), 256, 0, stream>>>(q, kbuf, s, alpha, aff);
  k_out_mfma<<<dim3(32, 2, B_), 256, 0, stream>>>(aff, xTh, x, out);
}

// Round 6
// 645.442 us; speedup vs baseline: 1.0382x; 1.0053x over previous
//
#include <hip/hip_runtime.h>
#include <math.h>

#define B_   32
#define C_   256
#define N_   4096
#define N8_  512
#define C8_  32
#define EPS_ 1e-5f

typedef __attribute__((ext_vector_type(8))) short short8;
typedef __attribute__((ext_vector_type(4))) float f32x4;

__device__ __forceinline__ ushort f2bf(float v) {
  unsigned u = __float_as_uint(v);
  unsigned r = (u + 0x7fffu + ((u >> 16) & 1u)) >> 16;  // RNE to bf16
  return (ushort)r;
}
__device__ __forceinline__ float bf2f(ushort h) {
  return __uint_as_float(((unsigned)h) << 16);
}

// ------------- fp32 -> (bf16 hi, bf16 lo) split conversion (W) ------------
__global__ __launch_bounds__(256) void k_cvt(const float* __restrict__ src,
                                             ushort* __restrict__ hi,
                                             ushort* __restrict__ lo, int n4) {
  int i = blockIdx.x * 256 + threadIdx.x;
  int stride = gridDim.x * 256;
  for (; i < n4; i += stride) {
    float4 v = ((const float4*)src)[i];
    ushort4 h, l;
    h.x = f2bf(v.x); l.x = f2bf(v.x - bf2f(h.x));
    h.y = f2bf(v.y); l.y = f2bf(v.y - bf2f(h.y));
    h.z = f2bf(v.z); l.z = f2bf(v.z - bf2f(h.z));
    h.w = f2bf(v.w); l.w = f2bf(v.w - bf2f(h.w));
    ((ushort4*)hi)[i] = h;
    ((ushort4*)lo)[i] = l;
  }
}

// --- x converter: xh/xl flat [b][c][n], xTh transposed [b][n][c] (hi only),
// --- plus per-(b,c) max-pool partials over each 64-n block. One x read.
__global__ __launch_bounds__(256) void k_cvt_x(const float* __restrict__ x,
    ushort* __restrict__ xh, ushort* __restrict__ xl,
    ushort* __restrict__ xTh, float* __restrict__ partial) {
  int b = blockIdx.z, cb = blockIdx.y, nb = blockIdx.x;  // cb:0..3, nb:0..63
  int t = threadIdx.x;
  int cl  = t >> 2;          // 0..63
  int nl0 = (t & 3) * 16;    // 0,16,32,48
  const float* xp = x + ((size_t)b * C_ + cb * 64 + cl) * N_ + nb * 64 + nl0;
  float v[16];
  *(float4*)&v[0]  = *(const float4*)(xp + 0);
  *(float4*)&v[4]  = *(const float4*)(xp + 4);
  *(float4*)&v[8]  = *(const float4*)(xp + 8);
  *(float4*)&v[12] = *(const float4*)(xp + 12);
  ushort h[16], l[16];
  float mx = -3.402823466e+38f;
  #pragma unroll
  for (int j = 0; j < 16; ++j) {
    h[j] = f2bf(v[j]);
    l[j] = f2bf(v[j] - bf2f(h[j]));
    mx = fmaxf(mx, v[j]);
  }
  size_t fbase = ((size_t)b * C_ + cb * 64 + cl) * N_ + nb * 64 + nl0;
  *(short8*)(xh + fbase)     = *(short8*)&h[0];
  *(short8*)(xh + fbase + 8) = *(short8*)&h[8];
  *(short8*)(xl + fbase)     = *(short8*)&l[0];
  *(short8*)(xl + fbase + 8) = *(short8*)&l[8];
  // pool partial: reduce 4 threads sharing c
  mx = fmaxf(mx, __shfl_xor(mx, 1, 64));
  mx = fmaxf(mx, __shfl_xor(mx, 2, 64));
  if ((t & 3) == 0)
    partial[((size_t)b * C_ + cb * 64 + cl) * 64 + nb] = mx;
  // LDS transpose of hi
  __shared__ ushort lds[64 * 66];
  #pragma unroll
  for (int j = 0; j < 16; ++j) lds[cl * 66 + nl0 + j] = h[j];
  __syncthreads();
  int nr = t >> 2;           // 0..63
  int c0 = (t & 3) * 16;
  ushort o[16];
  #pragma unroll
  for (int j = 0; j < 16; ++j) o[j] = lds[(c0 + j) * 66 + nr];
  size_t tbase = ((size_t)b * N_ + nb * 64 + nr) * C_ + cb * 64 + c0;
  *(short8*)(xTh + tbase)     = *(short8*)&o[0];
  *(short8*)(xTh + tbase + 8) = *(short8*)&o[8];
}

// -------- kernel 1b: s = sigmoid(relu(pool@W1^T)@W2^T), pool from partials -
__global__ __launch_bounds__(256) void k_semlp(const float* __restrict__ partial,
                                               const float* __restrict__ W1,
                                               const float* __restrict__ W2,
                                               float* __restrict__ s) {
  int b = blockIdx.x, t = threadIdx.x;
  __shared__ float p[C_];
  __shared__ float h[C8_];
  float m = -3.402823466e+38f;
  const float* pp = partial + ((size_t)b * C_ + t) * 64;
  #pragma unroll
  for (int j = 0; j < 64; ++j) m = fmaxf(m, pp[j]);
  p[t] = m;
  __syncthreads();
  if (t < C8_) {
    float a = 0.f;
    for (int c = 0; c < C_; ++c) a = fmaf(p[c], W1[t * C_ + c], a);
    h[t] = fmaxf(a, 0.f);
  }
  __syncthreads();
  float a = 0.f;
  #pragma unroll
  for (int j = 0; j < C8_; ++j) a = fmaf(h[j], W2[t * C8_ + j], a);
  s[b * C_ + t] = 1.f / (1.f + __expf(-a));
}

// ------- kernel 2 (MFMA, rolling pipeline): split-K partial GEMM for q|k --
// D[b] (1024 x 256) = [Wq;Wk](1024 x K') @ X[b]^T(K' x 256), K' = 3*4096:
// seg0 (Wh,Xh) tiles 0..63, seg1 (Wl,Xh) 64..127, seg2 (Wh,Xl) 128..191.
// 256x256 tile, BK=64, 8 waves.  split-K=2: ks half processes tiles
// gbase..gbase+95 (gbase = ks*96).  XCD-swizzled grid, 3-bit XOR LDS swizzle.
// Per tile: 8 m-steps {2 ds_read next A-row || 8 MFMA}; B refilled step 7.
#define GLD16(SRC, DSTP) __builtin_amdgcn_global_load_lds( \
    (const __attribute__((address_space(1))) void*)(SRC), \
    (__attribute__((address_space(3))) void*)(DSTP), 16, 0, 0)

__global__ __launch_bounds__(512, 2) void k_qk8(
    const ushort* __restrict__ wh, const ushort* __restrict__ wl,
    const ushort* __restrict__ xh, const ushort* __restrict__ xl,
    float* __restrict__ part) {
  __shared__ ushort lds[2][2][256 * 64];   // [buf][A|B][row*64+col] 128 KiB
  const int bid = blockIdx.x;
  const int xcd = bid & 7, slot = bid >> 3;
  const int b   = xcd * 4 + (slot & 3);    // same-b blocks share an XCD
  const int role = slot >> 2;              // 0..7
  const int ks = role & 1;                 // split-K half
  const int mt = role >> 1;                // 256-row M tile
  const int t = threadIdx.x;
  const int lane = t & 63, wave = t >> 6;
  const int wm = wave >> 2, wn = wave & 3;     // 2M x 4N wave grid
  const int fr = lane & 15, quad = lane >> 4;
  const int R0 = mt * 256;
  const int tr = t >> 3, tc = (t & 7) << 3;    // staging row / ushort col
  int aro[4], bro[4];
#pragma unroll
  for (int j = 0; j < 4; ++j) {
    int rl = j * 64 + tr;                       // tile-local row 0..255
    int cu = tc ^ ((rl & 7) << 3);              // pre-swizzled source col
    aro[j] = (R0 + rl) * N_ + cu;
    bro[j] = (b * C_ + rl) * N_ + cu;
  }
  const int dl = t * 8;                         // linear LDS dest (ushorts)

  f32x4 acc[8][4];
#pragma unroll
  for (int m = 0; m < 8; ++m)
#pragma unroll
    for (int n = 0; n < 4; ++n) acc[m][n] = (f32x4){0.f, 0.f, 0.f, 0.f};

  short8 afA_[2], afB_[2];       // rolling A-row pair (2 k-slots each)
  short8 b0[2][2], b1[2][2];     // B fragments, both NH halves

#define STG(AP, BP, K0, P) do { \
    GLD16((AP) + (aro[0] + (K0)), &lds[P][0][0 * 4096 + dl]); \
    GLD16((AP) + (aro[1] + (K0)), &lds[P][0][1 * 4096 + dl]); \
    GLD16((AP) + (aro[2] + (K0)), &lds[P][0][2 * 4096 + dl]); \
    GLD16((AP) + (aro[3] + (K0)), &lds[P][0][3 * 4096 + dl]); \
    GLD16((BP) + (bro[0] + (K0)), &lds[P][1][0 * 4096 + dl]); \
    GLD16((BP) + (bro[1] + (K0)), &lds[P][1][1 * 4096 + dl]); \
    GLD16((BP) + (bro[2] + (K0)), &lds[P][1][2 * 4096 + dl]); \
    GLD16((BP) + (bro[3] + (K0)), &lds[P][1][3 * 4096 + dl]); \
  } while (0)
#define VMC8 asm volatile("s_waitcnt vmcnt(8)" ::: "memory")
#define VMC0 asm volatile("s_waitcnt vmcnt(0)" ::: "memory")
#define LGKM0 asm volatile("s_waitcnt lgkmcnt(0)" ::: "memory")
#define BARF() do { __builtin_amdgcn_s_barrier(); \
                    __builtin_amdgcn_sched_barrier(0); } while (0)
#define MFMA_(A, Bb, Cc) __builtin_amdgcn_mfma_f32_16x16x32_bf16(A, Bb, Cc, 0, 0, 0)
#define RDROW(P, DST, RIDX) do { \
    int rr_ = wm * 128 + (RIDX) * 16 + fr; \
    int o_ = (rr_ << 6); int sw_ = (rr_ & 7) << 3; \
    DST[0] = *(const short8*)&lds[P][0][o_ + ((quad << 3) ^ sw_)]; \
    DST[1] = *(const short8*)&lds[P][0][o_ + (((quad << 3) + 32) ^ sw_)]; \
  } while (0)
#define RDBX(P, BF, NH) do { \
    _Pragma("unroll") \
    for (int n = 0; n < 2; ++n) { \
      int c_ = wn * 64 + ((NH) * 2 + n) * 16 + fr; \
      int o_ = (c_ << 6); int sw_ = (c_ & 7) << 3; \
      BF[n][0] = *(const short8*)&lds[P][1][o_ + ((quad << 3) ^ sw_)]; \
      BF[n][1] = *(const short8*)&lds[P][1][o_ + (((quad << 3) + 32) ^ sw_)]; \
    } } while (0)
#define MM8(S, AF) do { \
    __builtin_amdgcn_s_setprio(1); \
    acc[S][0] = MFMA_(AF[0], b0[0][0], acc[S][0]); \
    acc[S][0] = MFMA_(AF[1], b0[0][1], acc[S][0]); \
    acc[S][1] = MFMA_(AF[0], b0[1][0], acc[S][1]); \
    acc[S][1] = MFMA_(AF[1], b0[1][1], acc[S][1]); \
    acc[S][2] = MFMA_(AF[0], b1[0][0], acc[S][2]); \
    acc[S][2] = MFMA_(AF[1], b1[0][1], acc[S][2]); \
    acc[S][3] = MFMA_(AF[0], b1[1][0], acc[S][3]); \
    acc[S][3] = MFMA_(AF[1], b1[1][1], acc[S][3]); \
    __builtin_amdgcn_s_setprio(0); } while (0)
#define MM4(S, AF, BF, CB) do { \
    __builtin_amdgcn_s_setprio(1); \
    acc[S][(CB) + 0] = MFMA_(AF[0], BF[0][0], acc[S][(CB) + 0]); \
    acc[S][(CB) + 0] = MFMA_(AF[1], BF[0][1], acc[S][(CB) + 0]); \
    acc[S][(CB) + 1] = MFMA_(AF[0], BF[1][0], acc[S][(CB) + 1]); \
    acc[S][(CB) + 1] = MFMA_(AF[1], BF[1][1], acc[S][(CB) + 1]); \
    __builtin_amdgcn_s_setprio(0); } while (0)
// One tile: steps 0-6 roll A rows r1..r7 under MFMA; then stage/handoff;
// step 7 finishes tile and prefetches next tile's A-r0 and B from PN.
#define BLOCK(P, PN, APs, BPs, KS, DOSTG, VMCST, DORD) do { \
    RDROW(P, afB_, 1); MM8(0, afA_); \
    RDROW(P, afA_, 2); MM8(1, afB_); \
    RDROW(P, afB_, 3); MM8(2, afA_); \
    RDROW(P, afA_, 4); MM8(3, afB_); \
    RDROW(P, afB_, 5); MM8(4, afA_); \
    RDROW(P, afA_, 6); MM8(5, afB_); \
    RDROW(P, afB_, 7); MM8(6, afA_); \
    LGKM0; \
    BARF(); \
    if (DOSTG) STG(APs, BPs, KS, P); \
    VMCST; \
    BARF(); \
    if (DORD) RDROW(PN, afA_, 0); \
    MM4(7, afB_, b0, 0); \
    if (DORD) RDBX(PN, b0, 0); \
    MM4(7, afB_, b1, 2); \
    if (DORD) RDBX(PN, b1, 1); \
  } while (0)

  const int gbase = ks * 96;   // this half's 96 K-tiles: gbase..gbase+95
  // ---- prologue: stage tiles gbase, gbase+1; load tile-gbase fragments ----
  {
    int g0 = gbase, s0 = g0 >> 6, k0p = (g0 & 63) << 6;
    const ushort* A0 = (s0 == 1) ? wl : wh;
    const ushort* B0 = (s0 == 2) ? xl : xh;
    STG(A0, B0, k0p, 0);
    int g1 = gbase + 1, s1 = g1 >> 6, k1p = (g1 & 63) << 6;
    const ushort* A1 = (s1 == 1) ? wl : wh;
    const ushort* B1 = (s1 == 2) ? xl : xh;
    STG(A1, B1, k1p, 1);
  }
  VMC8;                     // oldest 8 = tile gbase's loads done
  BARF();
  RDROW(0, afA_, 0);
  RDBX(0, b0, 0);
  RDBX(0, b1, 1);

#pragma unroll 1
  for (int i = 0; i < 47; ++i) {
    int g2 = gbase + 2 * i + 2, s2 = g2 >> 6, k2 = (g2 & 63) << 6;
    const ushort* A2 = (s2 == 1) ? wl : wh;
    const ushort* B2 = (s2 == 2) ? xl : xh;
    int g3 = gbase + 2 * i + 3, s3 = g3 >> 6, k3 = (g3 & 63) << 6;
    const ushort* A3 = (s3 == 1) ? wl : wh;
    const ushort* B3 = (s3 == 2) ? xl : xh;
    BLOCK(0, 1, A2, B2, k2, 1, VMC8, 1);   // tile gbase+2i   (buf0)
    BLOCK(1, 0, A3, B3, k3, 1, VMC8, 1);   // tile gbase+2i+1 (buf1)
  }
  BLOCK(0, 1, wh, xh, 0, 0, VMC0, 1);      // tile gbase+94: no stage, drain
  BLOCK(1, 0, wh, xh, 0, 0, VMC0, 0);      // tile gbase+95: final

  float* dst = part + ((size_t)(ks * 32 + b) * 1024) * 256;
#pragma unroll
  for (int m = 0; m < 8; ++m) {
    int row0 = R0 + wm * 128 + m * 16 + quad * 4;
#pragma unroll
    for (int r = 0; r < 4; ++r) {
#pragma unroll
      for (int n = 0; n < 4; ++n) {
        int col = wn * 64 + n * 16 + fr;
        dst[(size_t)(row0 + r) * 256 + col] = acc[m][n][r];
      }
    }
  }
#undef STG
#undef VMC8
#undef VMC0
#undef LGKM0
#undef BARF
#undef MFMA_
#undef RDROW
#undef RDBX
#undef MM8
#undef MM4
#undef BLOCK
}

// ------- kernel 2b: reduce split-K partials + BN + relu -> q, k -----------
__global__ __launch_bounds__(256) void k_qkred(
    const float* __restrict__ part,
    const float* __restrict__ g1, const float* __restrict__ b1,
    const float* __restrict__ m1, const float* __restrict__ v1,
    const float* __restrict__ g2, const float* __restrict__ b2,
    const float* __restrict__ m2, const float* __restrict__ v2,
    float* __restrict__ q, float* __restrict__ k) {
  int i = blockIdx.x * 256 + threadIdx.x;   // f32x4 index, 2,097,152 total
  int b = i >> 16;
  int rem = i & 65535;
  int row = rem >> 6;                       // 0..1023
  int c4 = (rem & 63) << 2;
  const float4* p = (const float4*)part;
  float4 u = p[i];
  float4 w = p[i + 2097152];
  bool isq = row < 512;
  int m = isq ? row : row - 512;
  float sc = (isq ? g1 : g2)[m] * rsqrtf((isq ? v1 : v2)[m] + EPS_);
  float bi = (isq ? b1 : b2)[m] - (isq ? m1 : m2)[m] * sc;
  float4 o;
  o.x = fmaxf(fmaf(u.x + w.x, sc, bi), 0.f);
  o.y = fmaxf(fmaf(u.y + w.y, sc, bi), 0.f);
  o.z = fmaxf(fmaf(u.z + w.z, sc, bi), 0.f);
  o.w = fmaxf(fmaf(u.w + w.w, sc, bi), 0.f);
  float* d = (isq ? q : k) + ((size_t)b * N8_ + m) * C_ + c4;
  *(float4*)d = o;
}

// -- kernel 3: sim -> stable softmax(-sim) -> fold alpha*s -> aff2 (bf16) --
__global__ __launch_bounds__(256) void k_simsoft(const float* __restrict__ q,
    const float* __restrict__ k, const float* __restrict__ s,
    const float* __restrict__ alpha, ushort* __restrict__ aff2) {
  int b = blockIdx.y, ct = blockIdx.x;
  int t = threadIdx.x;
  __shared__ float kT[N8_][16];
  const float* kb = k + (size_t)b * N8_ * C_;
  int c0 = ct * 16;
  for (int chunk = 0; chunk < N8_ / 16; ++chunk) {
    int row = chunk * 16 + (t >> 4);
    kT[row][t & 15] = kb[(size_t)row * C_ + c0 + (t & 15)];
  }
  __syncthreads();
  float acc[16];
  #pragma unroll
  for (int i = 0; i < 16; ++i) acc[i] = 0.f;
  const float* qb = q + (size_t)b * N8_ * C_;
  for (int kk = 0; kk < N8_; ++kk) {
    float qv = qb[(size_t)kk * C_ + t];
    float4 k0 = *(const float4*)&kT[kk][0];
    float4 k1 = *(const float4*)&kT[kk][4];
    float4 k2 = *(const float4*)&kT[kk][8];
    float4 k3 = *(const float4*)&kT[kk][12];
    acc[0]  = fmaf(k0.x, qv, acc[0]);  acc[1]  = fmaf(k0.y, qv, acc[1]);
    acc[2]  = fmaf(k0.z, qv, acc[2]);  acc[3]  = fmaf(k0.w, qv, acc[3]);
    acc[4]  = fmaf(k1.x, qv, acc[4]);  acc[5]  = fmaf(k1.y, qv, acc[5]);
    acc[6]  = fmaf(k1.z, qv, acc[6]);  acc[7]  = fmaf(k1.w, qv, acc[7]);
    acc[8]  = fmaf(k2.x, qv, acc[8]);  acc[9]  = fmaf(k2.y, qv, acc[9]);
    acc[10] = fmaf(k2.z, qv, acc[10]); acc[11] = fmaf(k2.w, qv, acc[11]);
    acc[12] = fmaf(k3.x, qv, acc[12]); acc[13] = fmaf(k3.y, qv, acc[13]);
    acc[14] = fmaf(k3.z, qv, acc[14]); acc[15] = fmaf(k3.w, qv, acc[15]);
  }
  int lane = t & 63, wid = t >> 6;
  __shared__ float wmin[16][4];
  __shared__ float wsum[16][4];
  #pragma unroll
  for (int i = 0; i < 16; ++i) {
    float v = acc[i];
    for (int off = 32; off > 0; off >>= 1) v = fminf(v, __shfl_xor(v, off, 64));
    if (lane == 0) wmin[i][wid] = v;
  }
  __syncthreads();
  float w[16];
  #pragma unroll
  for (int i = 0; i < 16; ++i) {
    float m = fminf(fminf(wmin[i][0], wmin[i][1]), fminf(wmin[i][2], wmin[i][3]));
    w[i] = __expf(m - acc[i]);
  }
  #pragma unroll
  for (int i = 0; i < 16; ++i) {
    float v = w[i];
    for (int off = 32; off > 0; off >>= 1) v += __shfl_xor(v, off, 64);
    if (lane == 0) wsum[i][wid] = v;
  }
  __syncthreads();
  float fac = alpha[0] * s[b * C_ + t];
  ushort* ab = aff2 + (size_t)b * C_ * C_;
  #pragma unroll
  for (int i = 0; i < 16; ++i) {
    float Z = wsum[i][0] + wsum[i][1] + wsum[i][2] + wsum[i][3];
    ab[(size_t)(c0 + i) * C_ + t] = f2bf(fac * w[i] / Z);
  }
}

// ------- kernel 4 (MFMA): out = aff2 @ x + x, A=aff_bf16, B=xTh -----------
__global__ __launch_bounds__(256) void k_out_mfma(
    const ushort* __restrict__ aff, const ushort* __restrict__ xTh,
    const float* __restrict__ x, float* __restrict__ out) {
  int b  = blockIdx.z;
  int cb = blockIdx.y;  // 0..1 : c block of 128
  int nb = blockIdx.x;  // 0..31: n block of 128
  __shared__ ushort Ah[128 * 32];
  __shared__ ushort Bh[128 * 32];
  int t = threadIdx.x, wave = t >> 6, lane = t & 63;
  int wr = (wave >> 1) * 64, wc = (wave & 1) * 64;
  int srow = wave * 16 + (lane >> 2);
  int skof = (lane & 3) * 8;
  size_t aoff = ((size_t)b * C_ + cb * 128 + srow) * C_ + skof;
  size_t boff = ((size_t)b * N_ + nb * 128 + srow) * C_ + skof;
  int lb0 = (wave * 16) * 32;

  f32x4 acc[4][4];
  #pragma unroll
  for (int mi = 0; mi < 4; ++mi)
    #pragma unroll
    for (int ni = 0; ni < 4; ++ni)
      acc[mi][ni] = (f32x4){0.f, 0.f, 0.f, 0.f};

  int fr = lane & 15, quad = lane >> 4;
  for (int k0 = 0; k0 < C_; k0 += 32) {
    #pragma unroll
    for (int seg = 0; seg < 2; ++seg) {
      size_t ga = aoff + (size_t)seg * 64 * C_ + k0;
      size_t gb = boff + (size_t)seg * 64 * C_ + k0;
      int lb = lb0 + seg * 64 * 32;
      __builtin_amdgcn_global_load_lds(
          (const __attribute__((address_space(1))) void*)(aff + ga),
          (__attribute__((address_space(3))) void*)(&Ah[lb]), 16, 0, 0);
      __builtin_amdgcn_global_load_lds(
          (const __attribute__((address_space(1))) void*)(xTh + gb),
          (__attribute__((address_space(3))) void*)(&Bh[lb]), 16, 0, 0);
    }
    __syncthreads();
    short8 af[4], bf[4];
    #pragma unroll
    for (int i = 0; i < 4; ++i) {
      af[i] = *(const short8*)&Ah[(wr + i * 16 + fr) * 32 + quad * 8];
      bf[i] = *(const short8*)&Bh[(wc + i * 16 + fr) * 32 + quad * 8];
    }
    #pragma unroll
    for (int mi = 0; mi < 4; ++mi)
      #pragma unroll
      for (int ni = 0; ni < 4; ++ni)
        acc[mi][ni] = __builtin_amdgcn_mfma_f32_16x16x32_bf16(
            af[mi], bf[ni], acc[mi][ni], 0, 0, 0);
    __syncthreads();
  }

  const float* xb = x + (size_t)b * C_ * N_;
  float* ob = out + (size_t)b * C_ * N_;
  int c0 = cb * 128 + wr + quad * 4;
  int n0 = nb * 128 + wc + fr;
  #pragma unroll
  for (int mi = 0; mi < 4; ++mi) {
    #pragma unroll
    for (int r = 0; r < 4; ++r) {
      int c = c0 + mi * 16 + r;
      #pragma unroll
      for (int ni = 0; ni < 4; ++ni) {
        int n = n0 + ni * 16;
        ob[(size_t)c * N_ + n] = acc[mi][ni][r] + xb[(size_t)c * N_ + n];
      }
    }
  }
}

extern "C" void kernel_launch(void* const* d_in, const int* in_sizes, int n_in,
                              void* d_out, int out_size, void* d_ws, size_t ws_size,
                              hipStream_t stream) {
  const float* x     = (const float*)d_in[0];
  const float* Wq    = (const float*)d_in[1];
  const float* g1    = (const float*)d_in[2];
  const float* b1    = (const float*)d_in[3];
  const float* m1    = (const float*)d_in[4];
  const float* v1    = (const float*)d_in[5];
  const float* Wk    = (const float*)d_in[6];
  const float* g2    = (const float*)d_in[7];
  const float* b2    = (const float*)d_in[8];
  const float* m2    = (const float*)d_in[9];
  const float* v2    = (const float*)d_in[10];
  const float* W1    = (const float*)d_in[11];
  const float* W2    = (const float*)d_in[12];
  const float* alpha = (const float*)d_in[13];
  float* out = (float*)d_out;

  float* ws      = (float*)d_ws;
  float* q       = ws;                                  // 4,194,304 f
  float* kbuf    = q + (size_t)B_ * N8_ * C_;           // 4,194,304 f
  float* partial = kbuf + (size_t)B_ * N8_ * C_;        //   524,288 f
  float* s       = partial + (size_t)B_ * C_ * 64;      //     8,192 f
  ushort* aff    = (ushort*)(s + B_ * C_);              // 2,097,152 u16
  ushort* xh     = aff + (size_t)B_ * C_ * C_;          // 33,554,432 u16
  ushort* xl     = xh + (size_t)B_ * C_ * N_;
  ushort* xTh    = xl + (size_t)B_ * C_ * N_;           // 33,554,432 u16
  ushort* wh     = xTh + (size_t)B_ * C_ * N_;          // 4,194,304 u16
  ushort* wl     = wh + (size_t)2 * N8_ * N_;

  // split-K GEMM partials live in d_out until k_out_mfma overwrites it
  float* gpart = (float*)d_out;                         // 2*32*1024*256 f

  k_cvt_x<<<dim3(64, 4, B_), 256, 0, stream>>>(x, xh, xl, xTh, partial);
  k_cvt<<<dim3(1024), 256, 0, stream>>>(Wq, wh, wl, N8_ * N_ / 4);
  k_cvt<<<dim3(1024), 256, 0, stream>>>(Wk, wh + (size_t)N8_ * N_,
                                        wl + (size_t)N8_ * N_, N8_ * N_ / 4);
  k_semlp<<<dim3(B_), 256, 0, stream>>>(partial, W1, W2, s);
  k_qk8<<<dim3(256), 512, 0, stream>>>(wh, wl, xh, xl, gpart);
  k_qkred<<<dim3(8192), 256, 0, stream>>>(gpart, g1, b1, m1, v1,
                                          g2, b2, m2, v2, q, kbuf);
  k_simsoft<<<dim3(16, B_), 256, 0, stream>>>(q, kbuf, s, alpha, aff);
  k_out_mfma<<<dim3(32, 2, B_), 256, 0, stream>>>(aff, xTh, x, out);
}